// Round 5
// baseline (90.425 us; speedup 1.0000x reference)
//
#include <hip/hip_runtime.h>

// AttentiveConv3d: B=2, C=128, T=16, H=W=28, heads=2, HS=64, K=27 (3x3x3, pad 1)
// Round 5: two kernels. qfield (s-field, 200KB in d_ws) + fully fused
// aweight+merge+proj over 16-position tiles (grid 1568).
//   Fused block: A) 32 threads: softmax over 27 s-neighbors -> masked aw LDS
//                B) merged[c][p] = sum_k aw[k,h(c),p] * x[c,p+off_k] -> LDS
//                C) 2co x 4p float4 register-tiled projection, W via L1/L2.

#define TT 16
#define HH 28
#define WW 28
#define CC 128
#define SP (TT * HH * WW)   // 12544 = 784*16
#define NPOS (2 * SP)       // 25088
#define HS 64
#define KT 27
#define TP 16               // positions per fused tile

__global__ __launch_bounds__(256) void qfield_kernel(
    const float* __restrict__ x, const float* __restrict__ q,
    float* __restrict__ s)
{
    __shared__ float sp[16][32];     // [h*8+g][pos_local]
    const int tid = threadIdx.x;
    const int pl  = tid & 31;
    const int g   = tid >> 5;        // channel group 0..7
    const int p   = blockIdx.x * 32 + pl;
    const int b   = p / SP;
    const int si  = p % SP;
    const float* xb = x + (size_t)b * CC * SP + si;

    float acc0 = 0.f, acc1 = 0.f;    // head 0 / head 1 partials
    #pragma unroll
    for (int j = 0; j < 16; ++j) {
        const int c = g * 16 + j;              // channel
        const float val = xb[(size_t)c * SP];
        const float qv  = q[(c & 1) * HS + (c >> 1)] * (1.0f / 64.0f);
        if (c & 1) acc1 += qv * val; else acc0 += qv * val;
    }
    sp[g][pl]     = acc0;
    sp[8 + g][pl] = acc1;
    __syncthreads();
    if (tid < 64) {
        const int h = tid >> 5, pp = tid & 31;
        float a = 0.f;
        #pragma unroll
        for (int g2 = 0; g2 < 8; ++g2) a += sp[h * 8 + g2][pp];
        s[h * NPOS + blockIdx.x * 32 + pp] = a;
    }
}

__global__ __launch_bounds__(256) void fused_kernel(
    const float* __restrict__ x, const float* __restrict__ s,
    const float* __restrict__ Wout, const float* __restrict__ bout,
    float* __restrict__ out)
{
    __shared__ float s_aw[KT][2][TP];      // masked attn weights, 3.4 KB
    __shared__ float s_m[CC][TP];          // merged tile, 8 KB

    const int blk = blockIdx.x;            // 2 * 784
    const int b   = blk / (SP / TP);
    const int p0  = (blk % (SP / TP)) * TP;
    const int tid = threadIdx.x;

    // ---- per-lane tap offsets (also used by phase B) ----
    const int lane = tid & 15;             // p within tile
    const int g    = tid >> 4;             // 0..15
    const int p    = p0 + lane;
    const int v = p % WW, u = (p / WW) % HH, t = p / (WW * HH);

    int   off[KT];
    bool  okk[KT];
    #pragma unroll
    for (int k = 0; k < KT; ++k) {
        const int dt = k / 9 - 1, du = (k / 3) % 3 - 1, dv = k % 3 - 1;
        const int tt = t + dt, uu = u + du, vv = v + dv;
        const bool ok = (unsigned)tt < TT && (unsigned)uu < HH && (unsigned)vv < WW;
        okk[k] = ok;
        off[k] = ok ? (tt * HH + uu) * WW + vv : p;   // safe addr; weight 0 if OOB
    }

    // ---- phase A: attention weights (32 threads: h x 16 p) ----
    if (tid < 2 * TP) {
        const int h  = tid >> 4;
        const int pl = tid & 15;
        const int pp = p0 + pl;
        const int av = pp % WW, au = (pp / WW) % HH, at = pp / (WW * HH);
        const float* sf = s + h * NPOS + b * SP;
        float l[KT], msk[KT];
        #pragma unroll
        for (int k = 0; k < KT; ++k) {
            const int dt = k / 9 - 1, du = (k / 3) % 3 - 1, dv = k % 3 - 1;
            const int tt = at + dt, uu = au + du, vv = av + dv;
            const bool ok = (unsigned)tt < TT && (unsigned)uu < HH && (unsigned)vv < WW;
            l[k]   = ok ? sf[(tt * HH + uu) * WW + vv] : 0.f;  // pad logit = 0
            msk[k] = ok ? 1.f : 0.f;
        }
        float m = l[0];
        #pragma unroll
        for (int k = 1; k < KT; ++k) m = fmaxf(m, l[k]);
        float sum = 0.f;
        #pragma unroll
        for (int k = 0; k < KT; ++k) { l[k] = __expf(l[k] - m); sum += l[k]; }
        const float inv = 1.f / sum;
        #pragma unroll
        for (int k = 0; k < KT; ++k)
            s_aw[k][h][pl] = l[k] * inv * msk[k];     // OOB weight folded to 0
    }
    __syncthreads();

    // ---- phase B: merged[c][lane] for c = g + 16*i ----
    {
        const int h = g & 1;               // c&1 == g&1
        float aw[KT];
        #pragma unroll
        for (int k = 0; k < KT; ++k) aw[k] = s_aw[k][h][lane];
        #pragma unroll 2
        for (int i = 0; i < 8; ++i) {
            const int c = g + 16 * i;
            const float* xc = x + (size_t)(b * CC + c) * SP;
            float a = 0.f;
            #pragma unroll
            for (int k = 0; k < KT; ++k) a += aw[k] * xc[off[k]];
            s_m[c][lane] = a;
        }
    }
    __syncthreads();

    // ---- phase C: y[co][p] = b[co] + sum_ci W[co][ci]*merged[ci][p] ----
    // 2 co x 4 p (float4) per thread: cog = tid>>2 (co = 2cog,2cog+1), vg = tid&3
    const int cog = tid >> 2;              // 0..63
    const int vg  = tid & 3;               // p = p0 + vg*4 + vec-lane
    const float4* w0 = (const float4*)(Wout + (size_t)(cog * 2 + 0) * CC);
    const float4* w1 = (const float4*)(Wout + (size_t)(cog * 2 + 1) * CC);

    const float b0 = bout[cog * 2 + 0];
    const float b1 = bout[cog * 2 + 1];
    float4 acc0 = make_float4(b0, b0, b0, b0);
    float4 acc1 = make_float4(b1, b1, b1, b1);

    #pragma unroll 8
    for (int q4 = 0; q4 < CC / 4; ++q4) {
        const float4 wa = w0[q4];
        const float4 wb = w1[q4];
        const float4 m0 = *(const float4*)&s_m[q4 * 4 + 0][vg * 4];
        const float4 m1 = *(const float4*)&s_m[q4 * 4 + 1][vg * 4];
        const float4 m2 = *(const float4*)&s_m[q4 * 4 + 2][vg * 4];
        const float4 m3 = *(const float4*)&s_m[q4 * 4 + 3][vg * 4];
        acc0.x += wa.x * m0.x + wa.y * m1.x + wa.z * m2.x + wa.w * m3.x;
        acc0.y += wa.x * m0.y + wa.y * m1.y + wa.z * m2.y + wa.w * m3.y;
        acc0.z += wa.x * m0.z + wa.y * m1.z + wa.z * m2.z + wa.w * m3.z;
        acc0.w += wa.x * m0.w + wa.y * m1.w + wa.z * m2.w + wa.w * m3.w;
        acc1.x += wb.x * m0.x + wb.y * m1.x + wb.z * m2.x + wb.w * m3.x;
        acc1.y += wb.x * m0.y + wb.y * m1.y + wb.z * m2.y + wb.w * m3.y;
        acc1.z += wb.x * m0.z + wb.y * m1.z + wb.z * m2.z + wb.w * m3.z;
        acc1.w += wb.x * m0.w + wb.y * m1.w + wb.z * m2.w + wb.w * m3.w;
    }

    const size_t ob = (size_t)b * CC * SP + p0 + vg * 4;
    *(float4*)&out[ob + (size_t)(cog * 2 + 0) * SP] = acc0;
    *(float4*)&out[ob + (size_t)(cog * 2 + 1) * SP] = acc1;
}

extern "C" void kernel_launch(void* const* d_in, const int* in_sizes, int n_in,
                              void* d_out, int out_size, void* d_ws, size_t ws_size,
                              hipStream_t stream) {
    const float* x    = (const float*)d_in[0];
    const float* q    = (const float*)d_in[1];
    const float* Wout = (const float*)d_in[2];
    const float* bout = (const float*)d_in[3];
    float* out = (float*)d_out;
    float* s   = (float*)d_ws;                 // 2 * 25088 floats = 200 KB

    qfield_kernel<<<dim3(NPOS / 32),      dim3(256), 0, stream>>>(x, q, s);
    fused_kernel <<<dim3(2 * (SP / TP)),  dim3(256), 0, stream>>>(x, s, Wout, bout, out);
}

// Round 6
// 66.785 us; speedup vs baseline: 1.3540x; 1.3540x over previous
//
#include <hip/hip_runtime.h>

// AttentiveConv3d: B=2, C=128, T=16, H=W=28, heads=2, HS=64, K=27 (3x3x3, pad 1)
// Round 6: round-4 decomposition (best so far), merge kernel vectorized.
//   K1 qfield : s[h][b][p] = sum_c q~[h,c] * x[b,c,p]              (200 KB)
//   K2 aweight: aw[b][h][k][p] softmax, OOB weights folded to 0    (5.4 MB)
//   K3 merge  : float4-per-thread, 9-row loads with dv register reuse
//   K4 proj   : out = W @ merged + b   (GEMM, 32-p tiles, LDS merged tile)

#define TT 16
#define HH 28
#define WW 28
#define CC 128
#define SP (TT * HH * WW)   // 12544 = 49*256 = 3136*4
#define NPOS (2 * SP)       // 25088
#define HS 64
#define KT 27

__global__ __launch_bounds__(256) void qfield_kernel(
    const float* __restrict__ x, const float* __restrict__ q,
    float* __restrict__ s)
{
    __shared__ float sp[16][32];     // [h*8+g][pos_local]
    const int tid = threadIdx.x;
    const int pl  = tid & 31;
    const int g   = tid >> 5;        // channel group 0..7
    const int p   = blockIdx.x * 32 + pl;
    const int b   = p / SP;
    const int si  = p % SP;
    const float* xb = x + (size_t)b * CC * SP + si;

    float acc0 = 0.f, acc1 = 0.f;    // head 0 / head 1 partials
    #pragma unroll
    for (int j = 0; j < 16; ++j) {
        const int c = g * 16 + j;              // channel
        const float val = xb[(size_t)c * SP];
        const float qv  = q[(c & 1) * HS + (c >> 1)] * (1.0f / 64.0f);
        if (c & 1) acc1 += qv * val; else acc0 += qv * val;
    }
    sp[g][pl]     = acc0;
    sp[8 + g][pl] = acc1;
    __syncthreads();
    if (tid < 64) {
        const int h = tid >> 5, pp = tid & 31;
        float a = 0.f;
        #pragma unroll
        for (int g2 = 0; g2 < 8; ++g2) a += sp[h * 8 + g2][pp];
        s[h * NPOS + blockIdx.x * 32 + pp] = a;
    }
}

// thread = (b, h, p);  aw[((b*2+h)*KT + k)*SP + p]
__global__ __launch_bounds__(256) void aweight_kernel(
    const float* __restrict__ s, float* __restrict__ aw)
{
    const int idx = blockIdx.x * 256 + threadIdx.x;   // 4*SP = 50176 exactly
    const int p = idx % SP;
    const int h = (idx / SP) & 1;
    const int b = idx / (2 * SP);
    const int v = p % WW, u = (p / WW) % HH, t = p / (WW * HH);
    const float* sf = s + h * NPOS + b * SP;

    float l[KT], msk[KT];
    #pragma unroll
    for (int k = 0; k < KT; ++k) {
        const int dt = k / 9 - 1, du = (k / 3) % 3 - 1, dv = k % 3 - 1;
        const int tt = t + dt, uu = u + du, vv = v + dv;
        const bool ok = (unsigned)tt < TT && (unsigned)uu < HH && (unsigned)vv < WW;
        l[k]   = ok ? sf[(tt * HH + uu) * WW + vv] : 0.f;  // OOB logit = 0 (pad)
        msk[k] = ok ? 1.f : 0.f;
    }
    float m = l[0];
    #pragma unroll
    for (int k = 1; k < KT; ++k) m = fmaxf(m, l[k]);
    float sum = 0.f;
    #pragma unroll
    for (int k = 0; k < KT; ++k) { l[k] = __expf(l[k] - m); sum += l[k]; }
    const float inv = 1.f / sum;
    float* awp = aw + (size_t)(b * 2 + h) * KT * SP + p;
    #pragma unroll
    for (int k = 0; k < KT; ++k)
        awp[(size_t)k * SP] = l[k] * inv * msk[k];   // OOB weight folded to 0
}

// thread = one float4 group of p for one (b,c). 9 row-windows, dv reuse in regs.
__global__ __launch_bounds__(256) void merge_kernel(
    const float* __restrict__ x, const float* __restrict__ aw,
    float* __restrict__ mrg)
{
    const int idx = blockIdx.x * 256 + threadIdx.x;    // 2*128*3136 / 256 blocks
    const int p4 = idx % (SP / 4);
    const int c  = (idx / (SP / 4)) % CC;
    const int b  = idx / (CC * (SP / 4));
    const int h  = c & 1;
    const int p0 = p4 * 4;
    const int v0 = p0 % WW;                 // 0,4,...,24 (row-aligned)
    const int u  = (p0 / WW) % HH;
    const int t  = p0 / (WW * HH);

    const float* xc  = x + (size_t)(b * CC + c) * SP;
    const float* awp = aw + (size_t)(b * 2 + h) * KT * SP + p0;

    float4 acc = make_float4(0.f, 0.f, 0.f, 0.f);
    const int vl = (v0 == 0)  ? 0  : v0 - 1;    // clamped edge addrs (aw=0 there)
    const int vr = (v0 == 24) ? 27 : v0 + 4;

    #pragma unroll
    for (int dt = -1; dt <= 1; ++dt) {
        #pragma unroll
        for (int du = -1; du <= 1; ++du) {
            const int tt = t + dt, uu = u + du;
            const bool rok = ((unsigned)tt < TT) && ((unsigned)uu < HH);
            const int rbase = rok ? (tt * HH + uu) * WW : 0;  // safe addr; aw=0 if row OOB
            const float4 a  = *(const float4*)&xc[rbase + v0];
            const float  xl = xc[rbase + vl];
            const float  xr = xc[rbase + vr];
            const int kb = ((dt + 1) * 3 + (du + 1)) * 3;     // k = kb + (dv+1)
            const float4 wm = *(const float4*)&awp[(size_t)(kb + 0) * SP];
            const float4 w0 = *(const float4*)&awp[(size_t)(kb + 1) * SP];
            const float4 wp = *(const float4*)&awp[(size_t)(kb + 2) * SP];
            // dv=-1: window (xl, a.x, a.y, a.z)
            acc.x += wm.x * xl;  acc.y += wm.y * a.x; acc.z += wm.z * a.y; acc.w += wm.w * a.z;
            // dv= 0: window a
            acc.x += w0.x * a.x; acc.y += w0.y * a.y; acc.z += w0.z * a.z; acc.w += w0.w * a.w;
            // dv=+1: window (a.y, a.z, a.w, xr)
            acc.x += wp.x * a.y; acc.y += wp.y * a.z; acc.z += wp.z * a.w; acc.w += wp.w * xr;
        }
    }
    ((float4*)mrg)[idx] = acc;
}

// block = 32-p tile of one batch; 256 threads = (cog 0..31) x (vg 0..7)
__global__ __launch_bounds__(256) void proj_kernel(
    const float* __restrict__ mrg, const float* __restrict__ Wout,
    const float* __restrict__ bout, float* __restrict__ out)
{
    __shared__ float s_m[CC][32];          // 16 KB
    const int pb  = blockIdx.x;            // 2 * 392
    const int b   = pb / (SP / 32);
    const int p0  = (pb % (SP / 32)) * 32;
    const int tid = threadIdx.x;

    // stage merged[128][p0..p0+32) -> LDS, fully coalesced float4
    const float4* src = (const float4*)(mrg + (size_t)b * CC * SP);
    float4* dst = (float4*)&s_m[0][0];
    #pragma unroll
    for (int j = tid; j < CC * 8; j += 256) {
        const int ci = j >> 3, col = j & 7;
        dst[j] = src[(size_t)ci * (SP / 4) + p0 / 4 + col];
    }
    __syncthreads();

    const int cog = tid >> 3;              // co = cog*4 + c
    const int vg  = tid & 7;               // p = p0 + vg*4 + (vec lane)
    const float4* w0 = (const float4*)(Wout + (size_t)(cog * 4 + 0) * CC);
    const float4* w1 = (const float4*)(Wout + (size_t)(cog * 4 + 1) * CC);
    const float4* w2 = (const float4*)(Wout + (size_t)(cog * 4 + 2) * CC);
    const float4* w3 = (const float4*)(Wout + (size_t)(cog * 4 + 3) * CC);

    float4 acc[4];
    #pragma unroll
    for (int c = 0; c < 4; ++c) {
        const float bb = bout[cog * 4 + c];
        acc[c] = make_float4(bb, bb, bb, bb);
    }

    #pragma unroll 8
    for (int q4 = 0; q4 < CC / 4; ++q4) {
        float4 w4[4] = { w0[q4], w1[q4], w2[q4], w3[q4] };
        float4 m0 = *(const float4*)&s_m[q4 * 4 + 0][vg * 4];
        float4 m1 = *(const float4*)&s_m[q4 * 4 + 1][vg * 4];
        float4 m2 = *(const float4*)&s_m[q4 * 4 + 2][vg * 4];
        float4 m3 = *(const float4*)&s_m[q4 * 4 + 3][vg * 4];
        #pragma unroll
        for (int c = 0; c < 4; ++c) {
            acc[c].x += w4[c].x * m0.x + w4[c].y * m1.x + w4[c].z * m2.x + w4[c].w * m3.x;
            acc[c].y += w4[c].x * m0.y + w4[c].y * m1.y + w4[c].z * m2.y + w4[c].w * m3.y;
            acc[c].z += w4[c].x * m0.z + w4[c].y * m1.z + w4[c].z * m2.z + w4[c].w * m3.z;
            acc[c].w += w4[c].x * m0.w + w4[c].y * m1.w + w4[c].z * m2.w + w4[c].w * m3.w;
        }
    }

    #pragma unroll
    for (int c = 0; c < 4; ++c) {
        const int co = cog * 4 + c;
        *(float4*)&out[(size_t)(b * CC + co) * SP + p0 + vg * 4] = acc[c];
    }
}

extern "C" void kernel_launch(void* const* d_in, const int* in_sizes, int n_in,
                              void* d_out, int out_size, void* d_ws, size_t ws_size,
                              hipStream_t stream) {
    const float* x    = (const float*)d_in[0];
    const float* q    = (const float*)d_in[1];
    const float* Wout = (const float*)d_in[2];
    const float* bout = (const float*)d_in[3];
    float* out = (float*)d_out;

    float* s   = (float*)d_ws;                       // 50176 floats
    float* aw  = s + NPOS;                           // 4*27*SP floats
    float* mrg = aw + (size_t)4 * KT * SP;           // 2*128*SP floats

    qfield_kernel <<<dim3(NPOS / 32),            dim3(256), 0, stream>>>(x, q, s);
    aweight_kernel<<<dim3(4 * SP / 256),         dim3(256), 0, stream>>>(s, aw);
    merge_kernel  <<<dim3(2 * CC * (SP / 4) / 256), dim3(256), 0, stream>>>(x, aw, mrg);
    proj_kernel   <<<dim3(2 * (SP / 32)),        dim3(256), 0, stream>>>(mrg, Wout, bout, out);
}

// Round 7
// 61.176 us; speedup vs baseline: 1.4781x; 1.0917x over previous
//
#include <hip/hip_runtime.h>

// AttentiveConv3d: B=2, C=128, T=16, H=W=28, heads=2, HS=64, K=27 (3x3x3, pad 1)
// Round 7: 3-kernel pipeline — fuse merge+proj to kill the mrg HBM round-trip.
//   K1 qfield : s[h][b][p] = sum_c q~[h,c] * x[b,c,p]              (200 KB)
//   K2 aweight: aw[b][h][k][p] softmax, OOB weights folded to 0    (5.4 MB)
//   K3 fusedmp: per 32-p tile: phase B (vectorized 9-row-window merge -> LDS),
//               phase C (4co x 4p float4 projection from LDS, W via L1/L2).

#define TT 16
#define HH 28
#define WW 28
#define CC 128
#define SP (TT * HH * WW)   // 12544 = 392*32
#define NPOS (2 * SP)       // 25088
#define HS 64
#define KT 27

__global__ __launch_bounds__(256) void qfield_kernel(
    const float* __restrict__ x, const float* __restrict__ q,
    float* __restrict__ s)
{
    __shared__ float sp[16][32];     // [h*8+g][pos_local]
    const int tid = threadIdx.x;
    const int pl  = tid & 31;
    const int g   = tid >> 5;        // channel group 0..7
    const int p   = blockIdx.x * 32 + pl;
    const int b   = p / SP;
    const int si  = p % SP;
    const float* xb = x + (size_t)b * CC * SP + si;

    float acc0 = 0.f, acc1 = 0.f;    // head 0 / head 1 partials
    #pragma unroll
    for (int j = 0; j < 16; ++j) {
        const int c = g * 16 + j;              // channel
        const float val = xb[(size_t)c * SP];
        const float qv  = q[(c & 1) * HS + (c >> 1)] * (1.0f / 64.0f);
        if (c & 1) acc1 += qv * val; else acc0 += qv * val;
    }
    sp[g][pl]     = acc0;
    sp[8 + g][pl] = acc1;
    __syncthreads();
    if (tid < 64) {
        const int h = tid >> 5, pp = tid & 31;
        float a = 0.f;
        #pragma unroll
        for (int g2 = 0; g2 < 8; ++g2) a += sp[h * 8 + g2][pp];
        s[h * NPOS + blockIdx.x * 32 + pp] = a;
    }
}

// thread = (b, h, p);  aw[((b*2+h)*KT + k)*SP + p]
__global__ __launch_bounds__(256) void aweight_kernel(
    const float* __restrict__ s, float* __restrict__ aw)
{
    const int idx = blockIdx.x * 256 + threadIdx.x;   // 4*SP = 50176 exactly
    const int p = idx % SP;
    const int h = (idx / SP) & 1;
    const int b = idx / (2 * SP);
    const int v = p % WW, u = (p / WW) % HH, t = p / (WW * HH);
    const float* sf = s + h * NPOS + b * SP;

    float l[KT], msk[KT];
    #pragma unroll
    for (int k = 0; k < KT; ++k) {
        const int dt = k / 9 - 1, du = (k / 3) % 3 - 1, dv = k % 3 - 1;
        const int tt = t + dt, uu = u + du, vv = v + dv;
        const bool ok = (unsigned)tt < TT && (unsigned)uu < HH && (unsigned)vv < WW;
        l[k]   = ok ? sf[(tt * HH + uu) * WW + vv] : 0.f;  // OOB logit = 0 (pad)
        msk[k] = ok ? 1.f : 0.f;
    }
    float m = l[0];
    #pragma unroll
    for (int k = 1; k < KT; ++k) m = fmaxf(m, l[k]);
    float sum = 0.f;
    #pragma unroll
    for (int k = 0; k < KT; ++k) { l[k] = __expf(l[k] - m); sum += l[k]; }
    const float inv = 1.f / sum;
    float* awp = aw + (size_t)(b * 2 + h) * KT * SP + p;
    #pragma unroll
    for (int k = 0; k < KT; ++k)
        awp[(size_t)k * SP] = l[k] * inv * msk[k];   // OOB weight folded to 0
}

// block = 32-p tile of one batch; phase B: merged tile -> LDS (vectorized),
// phase C: projection (cog 0..31 x vg 0..7, 4co x 4p float4 each).
__global__ __launch_bounds__(256) void fusedmp_kernel(
    const float* __restrict__ x, const float* __restrict__ aw,
    const float* __restrict__ Wout, const float* __restrict__ bout,
    float* __restrict__ out)
{
    __shared__ float s_m[CC][32];          // 16 KB
    const int pb  = blockIdx.x;            // 2 * 392
    const int b   = pb / (SP / 32);
    const int p0  = (pb % (SP / 32)) * 32;
    const int tid = threadIdx.x;

    // ---- phase B: 1024 float4-tasks (c x 8 p4-groups), 4 per thread ----
    #pragma unroll
    for (int it = 0; it < 4; ++it) {
        const int task = it * 256 + tid;   // 0..1023
        const int c    = task >> 3;
        const int p4g  = task & 7;
        const int p    = p0 + p4g * 4;
        const int v0   = p % WW;           // 4-aligned, never crosses a row
        const int u    = (p / WW) % HH;
        const int t    = p / (WW * HH);
        const int h    = c & 1;
        const float* xc  = x + (size_t)(b * CC + c) * SP;
        const float* awp = aw + (size_t)(b * 2 + h) * KT * SP + p;
        const int vl = (v0 == 0)  ? 0  : v0 - 1;   // clamped edges (aw=0 there)
        const int vr = (v0 == 24) ? 27 : v0 + 4;

        float4 acc = make_float4(0.f, 0.f, 0.f, 0.f);
        #pragma unroll
        for (int dt = -1; dt <= 1; ++dt) {
            #pragma unroll
            for (int du = -1; du <= 1; ++du) {
                const int tt = t + dt, uu = u + du;
                const bool rok = ((unsigned)tt < TT) && ((unsigned)uu < HH);
                const int rbase = rok ? (tt * HH + uu) * WW : 0;  // aw=0 if row OOB
                const float4 a  = *(const float4*)&xc[rbase + v0];
                const float  xl = xc[rbase + vl];
                const float  xr = xc[rbase + vr];
                const int kb = ((dt + 1) * 3 + (du + 1)) * 3;     // k = kb + (dv+1)
                const float4 wm = *(const float4*)&awp[(size_t)(kb + 0) * SP];
                const float4 w0 = *(const float4*)&awp[(size_t)(kb + 1) * SP];
                const float4 wp = *(const float4*)&awp[(size_t)(kb + 2) * SP];
                // dv=-1: (xl, a.x, a.y, a.z); dv=0: a; dv=+1: (a.y, a.z, a.w, xr)
                acc.x += wm.x * xl;  acc.y += wm.y * a.x; acc.z += wm.z * a.y; acc.w += wm.w * a.z;
                acc.x += w0.x * a.x; acc.y += w0.y * a.y; acc.z += w0.z * a.z; acc.w += w0.w * a.w;
                acc.x += wp.x * a.y; acc.y += wp.y * a.z; acc.z += wp.z * a.w; acc.w += wp.w * xr;
            }
        }
        *(float4*)&s_m[c][p4g * 4] = acc;
    }
    __syncthreads();

    // ---- phase C: y[co][p] = b[co] + sum_ci W[co][ci]*merged[ci][p] ----
    const int cog = tid >> 3;              // co = cog*4 + c
    const int vg  = tid & 7;               // p = p0 + vg*4 + (vec lane)
    const float4* w0 = (const float4*)(Wout + (size_t)(cog * 4 + 0) * CC);
    const float4* w1 = (const float4*)(Wout + (size_t)(cog * 4 + 1) * CC);
    const float4* w2 = (const float4*)(Wout + (size_t)(cog * 4 + 2) * CC);
    const float4* w3 = (const float4*)(Wout + (size_t)(cog * 4 + 3) * CC);

    float4 acc[4];
    #pragma unroll
    for (int c = 0; c < 4; ++c) {
        const float bb = bout[cog * 4 + c];
        acc[c] = make_float4(bb, bb, bb, bb);
    }

    #pragma unroll 8
    for (int q4 = 0; q4 < CC / 4; ++q4) {
        float4 w4[4] = { w0[q4], w1[q4], w2[q4], w3[q4] };
        float4 m0 = *(const float4*)&s_m[q4 * 4 + 0][vg * 4];
        float4 m1 = *(const float4*)&s_m[q4 * 4 + 1][vg * 4];
        float4 m2 = *(const float4*)&s_m[q4 * 4 + 2][vg * 4];
        float4 m3 = *(const float4*)&s_m[q4 * 4 + 3][vg * 4];
        #pragma unroll
        for (int c = 0; c < 4; ++c) {
            acc[c].x += w4[c].x * m0.x + w4[c].y * m1.x + w4[c].z * m2.x + w4[c].w * m3.x;
            acc[c].y += w4[c].x * m0.y + w4[c].y * m1.y + w4[c].z * m2.y + w4[c].w * m3.y;
            acc[c].z += w4[c].x * m0.z + w4[c].y * m1.z + w4[c].z * m2.z + w4[c].w * m3.z;
            acc[c].w += w4[c].x * m0.w + w4[c].y * m1.w + w4[c].z * m2.w + w4[c].w * m3.w;
        }
    }

    #pragma unroll
    for (int c = 0; c < 4; ++c) {
        const int co = cog * 4 + c;
        *(float4*)&out[(size_t)(b * CC + co) * SP + p0 + vg * 4] = acc[c];
    }
}

extern "C" void kernel_launch(void* const* d_in, const int* in_sizes, int n_in,
                              void* d_out, int out_size, void* d_ws, size_t ws_size,
                              hipStream_t stream) {
    const float* x    = (const float*)d_in[0];
    const float* q    = (const float*)d_in[1];
    const float* Wout = (const float*)d_in[2];
    const float* bout = (const float*)d_in[3];
    float* out = (float*)d_out;

    float* s  = (float*)d_ws;                        // 50176 floats
    float* aw = s + NPOS;                            // 4*27*SP floats

    qfield_kernel <<<dim3(NPOS / 32),    dim3(256), 0, stream>>>(x, q, s);
    aweight_kernel<<<dim3(4 * SP / 256), dim3(256), 0, stream>>>(s, aw);
    fusedmp_kernel<<<dim3(2 * (SP / 32)),dim3(256), 0, stream>>>(x, aw, Wout, bout, out);
}